// Round 1
// baseline (57422.192 us; speedup 1.0000x reference)
//
#include <hip/hip_runtime.h>

#define NB 256    // batch
#define NT 512    // T == MAXLEN
#define NI 512    // INPUTS == M
#define NH 512    // HIDDEN
#define NG 1536   // 3*H

typedef __attribute__((ext_vector_type(8))) short bf16x8;
typedef __attribute__((ext_vector_type(4))) float f32x4;

__device__ __forceinline__ unsigned short f2bf(float f) {
  unsigned int u = __float_as_uint(f);
  u = u + 0x7FFFu + ((u >> 16) & 1u);
  return (unsigned short)(u >> 16);
}
__device__ __forceinline__ float bflo(unsigned int p) { return __uint_as_float(p << 16); }
__device__ __forceinline__ float bfhi(unsigned int p) { return __uint_as_float(p & 0xffff0000u); }
__device__ __forceinline__ float sigm(float x) { return 1.f / (1.f + __expf(-x)); }

// ---------------- generic f32 -> bf16 cast ----------------
__global__ __launch_bounds__(256) void cast_f32_bf16(const float* __restrict__ s,
                                                     unsigned short* __restrict__ d, int n) {
  int i = blockIdx.x * 256 + threadIdx.x;
  int stride = gridDim.x * 256;
  for (; i < n; i += stride) d[i] = f2bf(s[i]);
}

// ---------------- init: xt(0) gather, h = 0 ----------------
// ABuf layout per row (stride 2048 bf16): [0:512)=xt_even [512:1024)=xt_odd [1024:1536)=h [1536:2048)=ctx
__global__ __launch_bounds__(256) void init_kernel(const float* __restrict__ x,
                                                   unsigned short* __restrict__ ABuf,
                                                   float* __restrict__ hbuf) {
  int idx = blockIdx.x * 256 + threadIdx.x;   // grid 512 -> 131072 = 256*512
  int b = idx >> 9, i = idx & 511;
  ABuf[b * 2048 + i] = f2bf(x[(size_t)b * (NI * NT) + (size_t)i * NT + 0]);
  ABuf[b * 2048 + 1024 + i] = 0;
  hbuf[idx] = 0.f;
}

// ---------------- K1: logits = [xt|h] @ Wa^T + b_attn ; gh = h @ Whh^T + b_hh ----------------
__global__ __launch_bounds__(256) void k1_attn_hh(const unsigned short* __restrict__ ABuf,
                                                  const unsigned short* __restrict__ Wa,
                                                  const unsigned short* __restrict__ Whh,
                                                  const float* __restrict__ b_attn,
                                                  const float* __restrict__ b_hh,
                                                  float* __restrict__ logits,
                                                  float* __restrict__ gh, int t) {
  int bid = blockIdx.x;
  int l = threadIdx.x & 63, w = threadIdx.x >> 6;
  int al = l & 15, kg = l >> 4;
  f32x4 acc[4] = {f32x4{0,0,0,0}, f32x4{0,0,0,0}, f32x4{0,0,0,0}, f32x4{0,0,0,0}};
  if (bid < 32) {  // logits: 4 row-tiles x 8 col-tiles of 64x64
    int ct = bid & 7, rt = bid >> 3;
    int row0 = rt * 64 + w * 16, col0 = ct * 64;
    const unsigned short* apx = ABuf + (size_t)(row0 + al) * 2048 + (t & 1) * 512;
    const unsigned short* aph = ABuf + (size_t)(row0 + al) * 2048 + 1024;
    for (int k = 0; k < 512; k += 32) {   // phase 1: x_t part (W cols 0..511)
      bf16x8 a = *(const bf16x8*)(apx + k + kg * 8);
#pragma unroll
      for (int c = 0; c < 4; ++c) {
        const unsigned short* wp = Wa + (size_t)(col0 + c * 16 + al) * 1024 + k + kg * 8;
        acc[c] = __builtin_amdgcn_mfma_f32_16x16x32_bf16(a, *(const bf16x8*)wp, acc[c], 0, 0, 0);
      }
    }
    for (int k = 0; k < 512; k += 32) {   // phase 2: h part (W cols 512..1023)
      bf16x8 a = *(const bf16x8*)(aph + k + kg * 8);
#pragma unroll
      for (int c = 0; c < 4; ++c) {
        const unsigned short* wp = Wa + (size_t)(col0 + c * 16 + al) * 1024 + 512 + k + kg * 8;
        acc[c] = __builtin_amdgcn_mfma_f32_16x16x32_bf16(a, *(const bf16x8*)wp, acc[c], 0, 0, 0);
      }
    }
#pragma unroll
    for (int c = 0; c < 4; ++c) {
      int col = col0 + c * 16 + al;
#pragma unroll
      for (int r = 0; r < 4; ++r) {
        int row = row0 + kg * 4 + r;
        logits[row * NI + col] = acc[c][r] + b_attn[col];
      }
    }
  } else {  // gh: 4 row-tiles x 24 col-tiles
    int b2 = bid - 32;
    int ct = b2 % 24, rt = b2 / 24;
    int row0 = rt * 64 + w * 16, col0 = ct * 64;
    const unsigned short* aph = ABuf + (size_t)(row0 + al) * 2048 + 1024;
    for (int k = 0; k < 512; k += 32) {
      bf16x8 a = *(const bf16x8*)(aph + k + kg * 8);
#pragma unroll
      for (int c = 0; c < 4; ++c) {
        const unsigned short* wp = Whh + (size_t)(col0 + c * 16 + al) * 512 + k + kg * 8;
        acc[c] = __builtin_amdgcn_mfma_f32_16x16x32_bf16(a, *(const bf16x8*)wp, acc[c], 0, 0, 0);
      }
    }
#pragma unroll
    for (int c = 0; c < 4; ++c) {
      int col = col0 + c * 16 + al;
#pragma unroll
      for (int r = 0; r < 4; ++r) {
        int row = row0 + kg * 4 + r;
        gh[row * NG + col] = acc[c][r] + b_hh[col];
      }
    }
  }
}

// ---------------- K2: softmax(logits row) -> aw ; ctx = aw @ X_b ; write ctx bf16 ----------------
__global__ __launch_bounds__(256) void k2_softmax_ctx(const float* __restrict__ logits,
                                                      const unsigned short* __restrict__ Xc,
                                                      unsigned short* __restrict__ ABuf) {
  __shared__ float aw[512];
  __shared__ float red[8];
  int b = blockIdx.x, tid = threadIdx.x;
  float v0 = logits[b * NI + 2 * tid];
  float v1 = logits[b * NI + 2 * tid + 1];
  float m = fmaxf(v0, v1);
#pragma unroll
  for (int off = 32; off >= 1; off >>= 1) m = fmaxf(m, __shfl_xor(m, off));
  if ((tid & 63) == 0) red[tid >> 6] = m;
  __syncthreads();
  m = fmaxf(fmaxf(red[0], red[1]), fmaxf(red[2], red[3]));
  float e0 = __expf(v0 - m), e1 = __expf(v1 - m);
  float s = e0 + e1;
#pragma unroll
  for (int off = 32; off >= 1; off >>= 1) s += __shfl_xor(s, off);
  if ((tid & 63) == 0) red[4 + (tid >> 6)] = s;
  __syncthreads();
  s = (red[4] + red[5]) + (red[6] + red[7]);
  float inv = 1.f / s;
  aw[2 * tid] = e0 * inv;
  aw[2 * tid + 1] = e1 * inv;
  __syncthreads();

  const unsigned int* Xrow = (const unsigned int*)Xc + ((size_t)b << 17) + tid;  // uint view, 256 uints per m-row
  float a00 = 0.f, a01 = 0.f, a10 = 0.f, a11 = 0.f, a20 = 0.f, a21 = 0.f, a30 = 0.f, a31 = 0.f;
#pragma unroll 4
  for (int mm = 0; mm < 512; mm += 4) {
    unsigned int p0 = Xrow[(mm + 0) * 256];
    unsigned int p1 = Xrow[(mm + 1) * 256];
    unsigned int p2 = Xrow[(mm + 2) * 256];
    unsigned int p3 = Xrow[(mm + 3) * 256];
    float w0 = aw[mm], w1 = aw[mm + 1], w2 = aw[mm + 2], w3 = aw[mm + 3];
    a00 = fmaf(w0, bflo(p0), a00); a01 = fmaf(w0, bfhi(p0), a01);
    a10 = fmaf(w1, bflo(p1), a10); a11 = fmaf(w1, bfhi(p1), a11);
    a20 = fmaf(w2, bflo(p2), a20); a21 = fmaf(w2, bfhi(p2), a21);
    a30 = fmaf(w3, bflo(p3), a30); a31 = fmaf(w3, bfhi(p3), a31);
  }
  float c0 = (a00 + a10) + (a20 + a30);
  float c1 = (a01 + a11) + (a21 + a31);
  ABuf[b * 2048 + 1536 + 2 * tid] = f2bf(c0);
  ABuf[b * 2048 + 1536 + 2 * tid + 1] = f2bf(c1);
}

// ---------------- K3: g = relu([xt|ctx] @ Wc^T + b_comb) ; plus gather xt(t+1) ----------------
__global__ __launch_bounds__(256) void k3_comb(unsigned short* __restrict__ ABuf,
                                               const unsigned short* __restrict__ Wc,
                                               const float* __restrict__ b_comb,
                                               unsigned short* __restrict__ g_bf,
                                               const float* __restrict__ x, int t) {
  int bid = blockIdx.x;
  int l = threadIdx.x & 63, w = threadIdx.x >> 6;
  int al = l & 15, kg = l >> 4;
  if (bid < 32) {
    int ct = bid & 7, rt = bid >> 3;
    int row0 = rt * 64 + w * 16, col0 = ct * 64;
    f32x4 acc[4] = {f32x4{0,0,0,0}, f32x4{0,0,0,0}, f32x4{0,0,0,0}, f32x4{0,0,0,0}};
    const unsigned short* apx = ABuf + (size_t)(row0 + al) * 2048 + (t & 1) * 512;
    const unsigned short* apc = ABuf + (size_t)(row0 + al) * 2048 + 1536;
    for (int k = 0; k < 512; k += 32) {   // x_t part (Wc cols 0..511)
      bf16x8 a = *(const bf16x8*)(apx + k + kg * 8);
#pragma unroll
      for (int c = 0; c < 4; ++c) {
        const unsigned short* wp = Wc + (size_t)(col0 + c * 16 + al) * 1024 + k + kg * 8;
        acc[c] = __builtin_amdgcn_mfma_f32_16x16x32_bf16(a, *(const bf16x8*)wp, acc[c], 0, 0, 0);
      }
    }
    for (int k = 0; k < 512; k += 32) {   // ctx part (Wc cols 512..1023)
      bf16x8 a = *(const bf16x8*)(apc + k + kg * 8);
#pragma unroll
      for (int c = 0; c < 4; ++c) {
        const unsigned short* wp = Wc + (size_t)(col0 + c * 16 + al) * 1024 + 512 + k + kg * 8;
        acc[c] = __builtin_amdgcn_mfma_f32_16x16x32_bf16(a, *(const bf16x8*)wp, acc[c], 0, 0, 0);
      }
    }
#pragma unroll
    for (int c = 0; c < 4; ++c) {
      int col = col0 + c * 16 + al;
#pragma unroll
      for (int r = 0; r < 4; ++r) {
        int row = row0 + kg * 4 + r;
        float g = acc[c][r] + b_comb[col];
        g_bf[row * NH + col] = f2bf(fmaxf(g, 0.f));
      }
    }
  } else {  // gather x_{t+1} into parity slot
    if (t == NT - 1) return;
    int idx0 = (bid - 32) * 256 + threadIdx.x;  // 16 blocks * 256 threads
    int slot = ((t + 1) & 1) * 512;
#pragma unroll 8
    for (int r = 0; r < 32; ++r) {
      int e = idx0 + r * 4096;
      int b = e >> 9, i = e & 511;
      ABuf[b * 2048 + slot + i] = f2bf(x[(size_t)b * (NI * NT) + (size_t)i * NT + (t + 1)]);
    }
  }
}

// ---------------- K4: gi = g @ Wih^T + b_ih ; gates ; h' ----------------
__global__ __launch_bounds__(256) void k4_gru(const unsigned short* __restrict__ g_bf,
                                              const unsigned short* __restrict__ Wih,
                                              const float* __restrict__ b_ih,
                                              const float* __restrict__ gh,
                                              float* __restrict__ hbuf,
                                              unsigned short* __restrict__ ABuf) {
  int bid = blockIdx.x;
  int l = threadIdx.x & 63, w = threadIdx.x >> 6;
  int al = l & 15, kg = l >> 6 ? 0 : (l >> 4);  // kg = l>>4 (0..3); guard no-op
  kg = l >> 4;
  int ct = bid & 7, rt = bid >> 3;
  int j0 = ct * 64, row0 = rt * 64 + w * 16;
  f32x4 ar[4] = {f32x4{0,0,0,0}, f32x4{0,0,0,0}, f32x4{0,0,0,0}, f32x4{0,0,0,0}};
  f32x4 az[4] = {f32x4{0,0,0,0}, f32x4{0,0,0,0}, f32x4{0,0,0,0}, f32x4{0,0,0,0}};
  f32x4 an[4] = {f32x4{0,0,0,0}, f32x4{0,0,0,0}, f32x4{0,0,0,0}, f32x4{0,0,0,0}};
  const unsigned short* ap = g_bf + (size_t)(row0 + al) * 512;
  for (int k = 0; k < 512; k += 32) {
    bf16x8 a = *(const bf16x8*)(ap + k + kg * 8);
#pragma unroll
    for (int c = 0; c < 4; ++c) {
      int n = j0 + c * 16 + al;
      ar[c] = __builtin_amdgcn_mfma_f32_16x16x32_bf16(a, *(const bf16x8*)(Wih + (size_t)n * 512 + k + kg * 8), ar[c], 0, 0, 0);
      az[c] = __builtin_amdgcn_mfma_f32_16x16x32_bf16(a, *(const bf16x8*)(Wih + (size_t)(n + 512) * 512 + k + kg * 8), az[c], 0, 0, 0);
      an[c] = __builtin_amdgcn_mfma_f32_16x16x32_bf16(a, *(const bf16x8*)(Wih + (size_t)(n + 1024) * 512 + k + kg * 8), an[c], 0, 0, 0);
    }
  }
#pragma unroll
  for (int c = 0; c < 4; ++c) {
    int j = j0 + c * 16 + al;
#pragma unroll
    for (int r = 0; r < 4; ++r) {
      int row = row0 + kg * 4 + r;
      const float* ghrow = gh + (size_t)row * NG;
      float rg = sigm(ar[c][r] + b_ih[j] + ghrow[j]);
      float zg = sigm(az[c][r] + b_ih[j + 512] + ghrow[j + 512]);
      float ng = tanhf(an[c][r] + b_ih[j + 1024] + rg * ghrow[j + 1024]);
      float ho = hbuf[row * NH + j];
      float hn = (1.f - zg) * ng + zg * ho;
      hbuf[row * NH + j] = hn;
      ABuf[(size_t)row * 2048 + 1024 + j] = f2bf(hn);
    }
  }
}

// ---------------- K5: out = h @ Wout^T + b_out ----------------
__global__ __launch_bounds__(256) void k5_out(const unsigned short* __restrict__ ABuf,
                                              const unsigned short* __restrict__ Wout,
                                              const float* __restrict__ b_out,
                                              float* __restrict__ out) {
  int bid = blockIdx.x;
  int l = threadIdx.x & 63, w = threadIdx.x >> 6;
  int al = l & 15, kg = l >> 4;
  int ct = bid & 7, rt = bid >> 3;
  int row0 = rt * 64 + w * 16, col0 = ct * 64;
  f32x4 acc[4] = {f32x4{0,0,0,0}, f32x4{0,0,0,0}, f32x4{0,0,0,0}, f32x4{0,0,0,0}};
  const unsigned short* ap = ABuf + (size_t)(row0 + al) * 2048 + 1024;
  for (int k = 0; k < 512; k += 32) {
    bf16x8 a = *(const bf16x8*)(ap + k + kg * 8);
#pragma unroll
    for (int c = 0; c < 4; ++c) {
      const unsigned short* wp = Wout + (size_t)(col0 + c * 16 + al) * 512 + k + kg * 8;
      acc[c] = __builtin_amdgcn_mfma_f32_16x16x32_bf16(a, *(const bf16x8*)wp, acc[c], 0, 0, 0);
    }
  }
#pragma unroll
  for (int c = 0; c < 4; ++c) {
    int col = col0 + c * 16 + al;
#pragma unroll
    for (int r = 0; r < 4; ++r) {
      int row = row0 + kg * 4 + r;
      out[row * 512 + col] = acc[c][r] + b_out[col];
    }
  }
}

extern "C" void kernel_launch(void* const* d_in, const int* in_sizes, int n_in,
                              void* d_out, int out_size, void* d_ws, size_t ws_size,
                              hipStream_t stream) {
  const float* x      = (const float*)d_in[0];
  const float* W_attn = (const float*)d_in[1];
  const float* b_attn = (const float*)d_in[2];
  const float* W_comb = (const float*)d_in[3];
  const float* b_comb = (const float*)d_in[4];
  const float* W_ih   = (const float*)d_in[5];
  const float* W_hh   = (const float*)d_in[6];
  const float* b_ih   = (const float*)d_in[7];
  const float* b_hh   = (const float*)d_in[8];
  const float* W_out  = (const float*)d_in[9];
  const float* b_out  = (const float*)d_in[10];

  char* w = (char*)d_ws;
  size_t off = 0;
  unsigned short* Xc   = (unsigned short*)(w + off); off += (size_t)NB * NI * NT * 2;   // 128MB
  unsigned short* Wa   = (unsigned short*)(w + off); off += (size_t)NI * 1024 * 2;
  unsigned short* Whh  = (unsigned short*)(w + off); off += (size_t)NG * 512 * 2;
  unsigned short* Wc   = (unsigned short*)(w + off); off += (size_t)NH * 1024 * 2;
  unsigned short* Wih  = (unsigned short*)(w + off); off += (size_t)NG * 512 * 2;
  unsigned short* Wout = (unsigned short*)(w + off); off += (size_t)512 * 512 * 2;
  unsigned short* ABuf = (unsigned short*)(w + off); off += (size_t)NB * 2048 * 2;
  float* logits        = (float*)(w + off); off += (size_t)NB * NI * 4;
  float* gh            = (float*)(w + off); off += (size_t)NB * NG * 4;
  unsigned short* g_bf = (unsigned short*)(w + off); off += (size_t)NB * NH * 2;
  float* hbuf          = (float*)(w + off); off += (size_t)NB * NH * 4;

  cast_f32_bf16<<<8192, 256, 0, stream>>>(x, Xc, NB * NI * NT);
  cast_f32_bf16<<<512, 256, 0, stream>>>(W_attn, Wa, NI * 1024);
  cast_f32_bf16<<<512, 256, 0, stream>>>(W_hh, Whh, NG * 512);
  cast_f32_bf16<<<512, 256, 0, stream>>>(W_comb, Wc, NH * 1024);
  cast_f32_bf16<<<512, 256, 0, stream>>>(W_ih, Wih, NG * 512);
  cast_f32_bf16<<<512, 256, 0, stream>>>(W_out, Wout, 512 * 512);
  init_kernel<<<512, 256, 0, stream>>>(x, ABuf, hbuf);

  for (int t = 0; t < NT; ++t) {
    k1_attn_hh<<<128, 256, 0, stream>>>(ABuf, Wa, Whh, b_attn, b_hh, logits, gh, t);
    k2_softmax_ctx<<<256, 256, 0, stream>>>(logits, Xc, ABuf);
    k3_comb<<<48, 256, 0, stream>>>(ABuf, Wc, b_comb, g_bf, x, t);
    k4_gru<<<32, 256, 0, stream>>>(g_bf, Wih, b_ih, gh, hbuf, ABuf);
  }
  k5_out<<<32, 256, 0, stream>>>(ABuf, Wout, b_out, (float*)d_out);
}